// Round 13
// baseline (266.088 us; speedup 1.0000x reference)
//
#include <hip/hip_runtime.h>
#include <hip/hip_fp16.h>
#include <hip/hip_fp8.h>
#include <math.h>

// ---------------- problem constants ----------------
constexpr int NN   = 50000;          // nodes
constexpr int NE   = 800000;         // edges (before self loops)
constexpr int ETOT = NE + NN;        // 850000 with self loops
constexpr int F_IN = 128;
constexpr int HID  = 64;
constexpr int HEADS = 4;
constexpr int HC1  = HEADS * HID;    // 256
constexpr int NG   = 64;             // graphs
constexpr float SLOPE = 0.2f;
constexpr int TW_TOT = F_IN * HC1 + HC1 * HID;   // transpose work items (49152)
constexpr int CAP  = 128;            // bucket capacity per dst (max deg ~45 for this input)
constexpr int GEMM1_B = NN / 16;     // 3125 gemm blocks

// ---- atomic-free two-phase counting scatter ----
constexpr int CB_SHIFT = 7;                      // 128 dsts per coarse bucket
constexpr int NDB  = 1 << CB_SHIFT;              // 128
constexpr int NCB  = (NN + NDB - 1) >> CB_SHIFT; // 391 coarse buckets
constexpr int SEPB = 8192;                       // edges per scatter block
constexpr int SCAT_ITER = SEPB / (256 * 8);      // 4 macro-iterations
constexpr int NSB  = (ETOT + SEPB - 1) / SEPB;   // 104 scatter blocks

// h1/o1 channel permutation: group g = head*16 + lm (4 bytes tn=0..3),
// orig channel = head*64 + tn*16 + lm. Producer packs MFMA regs directly;
// consumers (gather4 groups, b1p, W2T K-axis) all use the same permutation.

typedef _Float16 half8 __attribute__((ext_vector_type(8)));
typedef float f32x4 __attribute__((ext_vector_type(4)));
typedef float f32x2 __attribute__((ext_vector_type(2)));

__device__ __forceinline__ float lrelu(float v) { return v >= 0.f ? v : SLOPE * v; }
// fast elu: exp(v)-1 (abs err ~1e-6 << 4e-3 tolerance; expm1f costs ~25 VALU)
__device__ __forceinline__ float elu(float v) { return v > 0.f ? v : __expf(v) - 1.f; }

// pack 8 floats -> 8 fp16 as one uint4
__device__ __forceinline__ uint4 pack8_h(const float* v) {
  union { __half2 h[4]; uint4 u; } pk;
  pk.h[0] = __floats2half2_rn(v[0], v[1]);
  pk.h[1] = __floats2half2_rn(v[2], v[3]);
  pk.h[2] = __floats2half2_rn(v[4], v[5]);
  pk.h[3] = __floats2half2_rn(v[6], v[7]);
  return pk.u;
}

// ---- fp8 e4m3 helpers (OCP; gfx950 HW cvt when available) ----
__device__ __forceinline__ unsigned pack_fp8x4(float a, float b, float c, float d) {
#if __has_builtin(__builtin_amdgcn_cvt_pk_fp8_f32)
  int v = 0;
  v = __builtin_amdgcn_cvt_pk_fp8_f32(a, b, v, false);
  v = __builtin_amdgcn_cvt_pk_fp8_f32(c, d, v, true);
  return (unsigned)v;
#else
  __hip_fp8_e4m3 fa(a), fb(b), fc(c), fd(d);
  return (unsigned)fa.__x | ((unsigned)fb.__x << 8) |
         ((unsigned)fc.__x << 16) | ((unsigned)fd.__x << 24);
#endif
}

__device__ __forceinline__ float fp8_1(unsigned byte) {   // manual e4m3fn -> f32
  unsigned s = (byte & 0x80u) << 24;
  unsigned em = (byte & 0x7fu) << 20;
  return __uint_as_float(s | em) * 0x1p+120f;
}

// 4-channel fp8 accumulate: acA gets bytes{0,1}, acB gets bytes{2,3}.
__device__ __forceinline__ void agg_ch4(f32x2& acA, f32x2& acB, unsigned u, float al) {
#if __has_builtin(__builtin_amdgcn_cvt_pk_f32_fp8)
  f32x2 lo = __builtin_amdgcn_cvt_pk_f32_fp8((int)u, false);
  f32x2 hi = __builtin_amdgcn_cvt_pk_f32_fp8((int)u, true);
  f32x2 a2 = {al, al};
  asm("v_pk_fma_f32 %0, %1, %2, %0" : "+v"(acA) : "v"(lo), "v"(a2));
  asm("v_pk_fma_f32 %0, %1, %2, %0" : "+v"(acB) : "v"(hi), "v"(a2));
#else
  acA[0] += al * fp8_1(u & 0xffu);
  acA[1] += al * fp8_1((u >> 8) & 0xffu);
  acB[0] += al * fp8_1((u >> 16) & 0xffu);
  acB[1] += al * fp8_1(u >> 24);
#endif
}

// ---- edge macro-load: 8 edges per thread at e0 (ETOT%8==0, NE%8==0) ----
__device__ __forceinline__ void load_edges8(const int* __restrict__ esrc,
                                            const int* __restrict__ edst,
                                            int e0, int* sarr, int* darr) {
  if (e0 < NE) {
    int4 a = *(const int4*)(esrc + e0);
    int4 b = *(const int4*)(esrc + e0 + 4);
    int4 c = *(const int4*)(edst + e0);
    int4 d4 = *(const int4*)(edst + e0 + 4);
    sarr[0]=a.x; sarr[1]=a.y; sarr[2]=a.z; sarr[3]=a.w;
    sarr[4]=b.x; sarr[5]=b.y; sarr[6]=b.z; sarr[7]=b.w;
    darr[0]=c.x; darr[1]=c.y; darr[2]=c.z; darr[3]=c.w;
    darr[4]=d4.x; darr[5]=d4.y; darr[6]=d4.z; darr[7]=d4.w;
  } else {                                // self-loops
#pragma unroll
    for (int k = 0; k < 8; ++k) { sarr[k] = e0 - NE + k; darr[k] = sarr[k]; }
  }
}

// ================= prep: weight transposes + b1 permute ==============================
__global__ void prep_kernel(const float* __restrict__ W1, const float* __restrict__ W2,
                            const float* __restrict__ b1,
                            __half* __restrict__ W1T, __half* __restrict__ W2T,
                            float* __restrict__ b1p) {
  int i = blockIdx.x * blockDim.x + threadIdx.x;
  if (i < F_IN * HC1) {                       // W1 [128][256] -> W1T [256][128]
    int k = i / HC1, n = i - k * HC1;
    W1T[n * F_IN + k] = __float2half(W1[i]);
  } else if (i < TW_TOT) {                    // W2 [256][64] -> W2T [64][256], K permuted
    int j = i - F_IN * HC1;
    int k = j / HID, n = j - k * HID;
    // kp(k): head=k>>6, tn=(k>>4)&3, lm=k&15 -> g=head*16+lm, k' = g*4+tn
    int kp = (((k >> 6) * 16 + (k & 15)) << 2) | ((k >> 4) & 3);
    W2T[n * HC1 + kp] = __float2half(W2[j]);
  } else if (i < TW_TOT + HC1) {
    int g4 = i - TW_TOT;
    int g = g4 >> 2, tn = g4 & 3;
    b1p[g4] = b1[(g >> 4) * 64 + tn * 16 + (g & 15)];
  }
}

// ================= mega kernel: atomic-free scatter blocks || gemm1 blocks ===========
__global__ __launch_bounds__(256) void gemm1_scatter_kernel(
    const float* __restrict__ x, const __half* __restrict__ W1T,
    const float* __restrict__ asrc, const float* __restrict__ adst,
    unsigned char* __restrict__ h1, float* __restrict__ ssrc, float* __restrict__ sdst,
    const int* __restrict__ esrc, const int* __restrict__ edst,
    int* __restrict__ blockcnt, int* __restrict__ blockoff, int* __restrict__ scmp) {
  const int t = threadIdx.x;
  if (blockIdx.x < NSB) {
    // ---- phase-1: block-local segmented scatter, ZERO global atomics ----
    __shared__ int hist[512];     // coarse histogram (padded to 512 for scan)
    __shared__ int buf2[512];     // scan double-buffer / base
    __shared__ int cursor[512];   // per-cb write cursor
    for (int i = t; i < 512; i += 256) { hist[i] = 0; cursor[i] = 0; }
    __syncthreads();
    const int ebase = blockIdx.x * SEPB;
    // pass A: histogram
    for (int it = 0; it < SCAT_ITER; ++it) {
      int e0 = ebase + it * 2048 + t * 8;
      if (e0 < ETOT) {
        int sarr[8], darr[8];
        load_edges8(esrc, edst, e0, sarr, darr);
#pragma unroll
        for (int k = 0; k < 8; ++k) atomicAdd(&hist[darr[k] >> CB_SHIFT], 1);
      }
    }
    __syncthreads();
    // per-block counts out (coalesced)
    for (int i = t; i < NCB; i += 256) blockcnt[blockIdx.x * NCB + i] = hist[i];
    // Hillis-Steele inclusive scan over 512 entries
    int* src = hist; int* dst = buf2;
    for (int off = 1; off < 512; off <<= 1) {
      for (int i = t; i < 512; i += 256) {
        int v = src[i];
        if (i >= off) v += src[i - off];
        dst[i] = v;
      }
      __syncthreads();
      int* tmp = src; src = dst; dst = tmp;
    }
    // exclusive base into dst; offsets out
    for (int i = t; i < NCB; i += 256) {
      int b = (i == 0) ? 0 : src[i - 1];
      dst[i] = b;
      blockoff[blockIdx.x * NCB + i] = ebase + b;
    }
    __syncthreads();
    // pass B: reload edges (L2-hot) and pack grouped-by-cb into own segment
    for (int it = 0; it < SCAT_ITER; ++it) {
      int e0 = ebase + it * 2048 + t * 8;
      if (e0 < ETOT) {
        int sarr[8], darr[8];
        load_edges8(esrc, edst, e0, sarr, darr);
#pragma unroll
        for (int k = 0; k < 8; ++k) {
          int d = darr[k];
          int cb = d >> CB_SHIFT;
          int pkv = sarr[k] | ((d & (NDB - 1)) << 16);   // src < 65536 fits 16 bits
          int slot = dst[cb] + atomicAdd(&cursor[cb], 1);  // LDS only
          scmp[ebase + slot] = pkv;                        // dense, own segment
        }
      }
    }
    return;
  }
  // ---- gemm1 part: NO LDS, scores + fp8 pack straight from MFMA registers ----
  const int m0 = (blockIdx.x - NSB) * 16;
  const int wv = t >> 6, lane = t & 63;
  const int lm = lane & 15, quad = lane >> 4;
  const int n0 = wv * 64;       // wave wv owns head wv's 64 channels
  const float*  arow  = x   + (size_t)(m0 + lm) * F_IN + quad * 8;
  const __half* wbase = W1T + (size_t)(n0 + lm) * F_IN + quad * 8;
  float4 xf[8];
#pragma unroll
  for (int it = 0; it < 4; ++it) {
    xf[it * 2 + 0] = *(const float4*)(arow + it * 32);
    xf[it * 2 + 1] = *(const float4*)(arow + it * 32 + 4);
  }
  half8 bh[4][4];   // [tn][it]
#pragma unroll
  for (int tn = 0; tn < 4; ++tn)
#pragma unroll
    for (int it = 0; it < 4; ++it)
      bh[tn][it] = *(const half8*)(wbase + tn * 16 * F_IN + it * 32);
  f32x4 acc[4] = {{0.f,0.f,0.f,0.f},{0.f,0.f,0.f,0.f},{0.f,0.f,0.f,0.f},{0.f,0.f,0.f,0.f}};
#pragma unroll
  for (int it = 0; it < 4; ++it) {
    float4 u = xf[it * 2 + 0], v = xf[it * 2 + 1];
    half8 a;
    a[0]=(_Float16)u.x; a[1]=(_Float16)u.y; a[2]=(_Float16)u.z; a[3]=(_Float16)u.w;
    a[4]=(_Float16)v.x; a[5]=(_Float16)v.y; a[6]=(_Float16)v.z; a[7]=(_Float16)v.w;
#pragma unroll
    for (int tn = 0; tn < 4; ++tn)
      acc[tn] = __builtin_amdgcn_mfma_f32_16x16x32_f16(a, bh[tn][it], acc[tn], 0, 0, 0);
  }
  // scores from registers: s[row][wv] = sum acc[tn][r] * a[n0+tn*16+lm], reduce over lm
  {
    float asv[4], adv[4];
#pragma unroll
    for (int tn = 0; tn < 4; ++tn) {
      asv[tn] = asrc[n0 + tn * 16 + lm];
      adv[tn] = adst[n0 + tn * 16 + lm];
    }
#pragma unroll
    for (int r = 0; r < 4; ++r) {
      float ps = acc[0][r] * asv[0] + acc[1][r] * asv[1]
               + acc[2][r] * asv[2] + acc[3][r] * asv[3];
      float pd = acc[0][r] * adv[0] + acc[1][r] * adv[1]
               + acc[2][r] * adv[2] + acc[3][r] * adv[3];
#pragma unroll
      for (int o = 1; o < 16; o <<= 1) {
        ps += __shfl_xor(ps, o, 64);
        pd += __shfl_xor(pd, o, 64);
      }
      if (lm == 0) {
        int row = m0 + quad * 4 + r;
        ssrc[row * HEADS + wv] = ps;
        sdst[row * HEADS + wv] = pd;
      }
    }
  }
  // h1 fp8 pack directly from registers into permuted layout:
  {
    const unsigned goff = (unsigned)((wv * 16 + lm) * 4);
#pragma unroll
    for (int r = 0; r < 4; ++r) {
      unsigned pk = pack_fp8x4(acc[0][r], acc[1][r], acc[2][r], acc[3][r]);
      *(unsigned*)(h1 + (size_t)(m0 + quad * 4 + r) * HC1 + goff) = pk;
    }
  }
}

// ================= phase-2: concatenate per-block runs into per-dst buckets =========
__global__ __launch_bounds__(1024) void bucket_build_kernel(
    const int* __restrict__ blockcnt, const int* __restrict__ blockoff,
    const int* __restrict__ scmp, int* __restrict__ cnt, int* __restrict__ bucket) {
  __shared__ int hist2[NDB];
  const int cb = blockIdx.x, t = threadIdx.x;
  const int wv = t >> 6, lane = t & 63;
  if (t < NDB) hist2[t] = 0;
  __syncthreads();
  for (int b = wv; b < NSB; b += 16) {
    int n   = blockcnt[b * NCB + cb];
    int off = blockoff[b * NCB + cb];
    for (int j = lane; j < n; j += 64) {
      int v = scmp[off + j];
      int s = v & 0xFFFF, dlow = (v >> 16) & (NDB - 1);
      int l = atomicAdd(&hist2[dlow], 1);
      if (l < CAP) bucket[(size_t)((cb << CB_SHIFT) | dlow) * CAP + l] = s;
    }
  }
  __syncthreads();
  int d = (cb << CB_SHIFT) | t;
  if (t < NDB && d < NN) cnt[d] = hist2[t];
}

// ================= fused GAT gather, layer 1 (H=4, fp8 h, permuted channels) =========
// One wave per dst. NEW agg layout (mirrors gather1's proven structure): 4 edge
// subgroups x 16 lanes x 16B uint4 chunk -> 4 edges in flight IN HARDWARE (immune
// to compiler load-sinking), 4x fewer load instructions, 4x shorter dep chains.
// Softmax phase + LDS alphas + saddr loads + fast elu retained.
__global__ __launch_bounds__(256) void gat_gather4_kernel(
    const int* __restrict__ cnt, const int* __restrict__ bucket,
    const float* __restrict__ ss, const float* __restrict__ sd,
    const unsigned char* __restrict__ h, const float* __restrict__ biasp,
    __half* __restrict__ outp) {
  __shared__ float paS[4][HEADS][40];    // [wave][head][slot], pitch 40 for bank spread
  const int wv   = threadIdx.x >> 6;
  const int lane = threadIdx.x & 63;
  const int d    = (blockIdx.x * 256 + threadIdx.x) >> 6;
  if (d >= NN) return;
  const int start = d * CAP;
  const int deg   = min(cnt[d], CAP);
  const int hsel  = lane & 3;            // softmax-phase head
  const int j0    = lane >> 2;           // softmax-phase edge
  const int eg    = lane >> 4;           // agg-phase edge subgroup (0..3)
  const int cpos  = lane & 15;           // agg: 16B chunk within 256B row
  const int head  = cpos >> 2;           // agg-phase head (4 groups per chunk, same head)
  const float sdv = sd[d * 4 + hsel];
  float (*pa)[40] = paS[wv];

  f32x2 ac[8];
#pragma unroll
  for (int k = 0; k < 8; ++k) ac[k] = (f32x2){0.f, 0.f};
  const unsigned laneoff = (unsigned)(cpos * 16);  // base h stays SGPR (saddr form)

  if (deg <= 32) {
    int s0 = 0, s1 = 0;
    float v0 = -INFINITY, v1 = -INFINITY;
    if (j0 < deg)      { s0 = bucket[start + j0];      v0 = lrelu(ss[s0 * 4 + hsel] + sdv); }
    if (j0 + 16 < deg) { s1 = bucket[start + j0 + 16]; v1 = lrelu(ss[s1 * 4 + hsel] + sdv); }
    float mx = fmaxf(v0, v1);
#pragma unroll
    for (int o = 4; o < 64; o <<= 1) mx = fmaxf(mx, __shfl_xor(mx, o, 64));
    float p0 = (j0 < deg)      ? __expf(v0 - mx) : 0.f;
    float p1 = (j0 + 16 < deg) ? __expf(v1 - mx) : 0.f;
    float den = p0 + p1;
#pragma unroll
    for (int o = 4; o < 64; o <<= 1) den += __shfl_xor(den, o, 64);
    const float inv = 1.f / (den + 1e-16f);
    pa[hsel][j0]      = p0 * inv;        // zeros where invalid -> pad slots are 0
    pa[hsel][j0 + 16] = p1 * inv;
    const int nq = (deg + 3) >> 2;
#pragma unroll
    for (int q = 0; q < 8; ++q) {
      if (q >= nq) break;                // wave-uniform exit
      int e = q * 4 + eg;                // this subgroup's edge (e < 32)
      float al = pa[head][e];            // 0 for pad slots
      unsigned sj = min((unsigned)bucket[start + e], (unsigned)(NN - 1));
      uint4 u = *(const uint4*)(h + ((sj << 8) + laneoff));
      agg_ch4(ac[0], ac[1], u.x, al);
      agg_ch4(ac[2], ac[3], u.y, al);
      agg_ch4(ac[4], ac[5], u.z, al);
      agg_ch4(ac[6], ac[7], u.w, al);
    }
  } else {
    // chunked (rare): 16 edges per chunk, alphas staged per chunk
    float mx = -INFINITY;
    for (int base = 0; base < deg; base += 16) {
      int j = base + j0;
      float v = (j < deg) ? lrelu(ss[bucket[start + j] * 4 + hsel] + sdv) : -INFINITY;
#pragma unroll
      for (int o = 4; o < 64; o <<= 1) v = fmaxf(v, __shfl_xor(v, o, 64));
      mx = fmaxf(mx, v);
    }
    float den = 0.f;
    for (int base = 0; base < deg; base += 16) {
      int j = base + j0;
      float p = (j < deg) ? __expf(lrelu(ss[bucket[start + j] * 4 + hsel] + sdv) - mx) : 0.f;
#pragma unroll
      for (int o = 4; o < 64; o <<= 1) p += __shfl_xor(p, o, 64);
      den += p;
    }
    const float inv = 1.f / (den + 1e-16f);
    for (int base = 0; base < deg; base += 16) {
      int j = base + j0;
      float pav = 0.f;
      if (j < deg) pav = __expf(lrelu(ss[bucket[start + j] * 4 + hsel] + sdv) - mx) * inv;
      pa[hsel][j0] = pav;                // all 16 slots rewritten; zeros where invalid
      const int m  = min(16, deg - base);
      const int nq = (m + 3) >> 2;
      for (int q = 0; q < nq; ++q) {
        int e = q * 4 + eg;              // local slot in [0,16)
        float al = pa[head][e];
        unsigned sj = min((unsigned)bucket[start + base + e], (unsigned)(NN - 1));
        uint4 u = *(const uint4*)(h + ((sj << 8) + laneoff));
        agg_ch4(ac[0], ac[1], u.x, al);
        agg_ch4(ac[2], ac[3], u.y, al);
        agg_ch4(ac[4], ac[5], u.z, al);
        agg_ch4(ac[6], ac[7], u.w, al);
      }
    }
  }
  // combine the 4 edge subgroups (2 shuffle rounds over 8 f32x2)
#pragma unroll
  for (int o = 16; o < 64; o <<= 1) {
#pragma unroll
    for (int k = 0; k < 8; ++k) {
      f32x2 tv;
      tv[0] = __shfl_xor(ac[k][0], o, 64);
      tv[1] = __shfl_xor(ac[k][1], o, 64);
      ac[k] += tv;
    }
  }
  if (eg == 0) {
    // lanes 0..15: 16 channels each; permuted bias + fast elu + fp16 store (32B/lane)
    float e[16];
#pragma unroll
    for (int k = 0; k < 16; ++k)
      e[k] = elu(ac[k >> 1][k & 1] + biasp[cpos * 16 + k]);
    __half* op = outp + (size_t)d * HC1 + cpos * 16;
    *(uint4*)op = pack8_h(e);
    *(uint4*)(op + 8) = pack8_h(e + 8);
  }
}

// ================= fused GAT gather, layer 2 (H=1, fp8 h): NO LDS ====================
__global__ __launch_bounds__(256) void gat_gather1_kernel(
    const int* __restrict__ cnt, const int* __restrict__ bucket,
    const float* __restrict__ ss, const float* __restrict__ sd,
    const unsigned char* __restrict__ h, const float* __restrict__ bias,
    float* __restrict__ outp) {
  const int lane = threadIdx.x & 63;
  const int d    = (blockIdx.x * 256 + threadIdx.x) >> 6;
  if (d >= NN) return;
  const int start = d * CAP;
  const int deg   = min(cnt[d], CAP);
  const int eg    = lane >> 4;    // edge subgroup (0..3)
  const int cpos  = lane & 15;    // 4B chunk within 64B fp8 row
  const float sdv = sd[d];
  f32x2 acA = {0.f, 0.f}, acB = {0.f, 0.f};
  const unsigned laneoff = (unsigned)(cpos * 4);

  if (deg <= 64) {
    int s = 0; float v = -INFINITY;
    if (lane < deg) { s = bucket[start + lane]; v = lrelu(ss[s] + sdv); }
    float mx = v;
#pragma unroll
    for (int o = 1; o < 64; o <<= 1) mx = fmaxf(mx, __shfl_xor(mx, o, 64));
    float p = (lane < deg) ? __expf(v - mx) : 0.f;
    float den = p;
#pragma unroll
    for (int o = 1; o < 64; o <<= 1) den += __shfl_xor(den, o, 64);
    const float par = p / (den + 1e-16f);   // 0 for lanes >= deg -> pad alpha 0
    const int nq = (deg + 3) >> 2;
#pragma unroll
    for (int q = 0; q < 16; ++q) {
      if (q >= nq) break;                   // wave-uniform exit
      int slot = q * 4 + eg;
      float al = __shfl(par, slot, 64);     // 0 automatically when slot >= deg
      int   sj = __shfl(s, slot, 64);       // 0 (valid row) when slot >= deg
      unsigned sc = min((unsigned)sj, (unsigned)(NN - 1));
      agg_ch4(acA, acB, *(const unsigned*)(h + ((sc << 6) + laneoff)), al);
    }
  } else {
    float mx = -INFINITY;
    for (int base = 0; base < deg; base += 64) {
      int j = base + lane;
      float v = (j < deg) ? lrelu(ss[bucket[start + j]] + sdv) : -INFINITY;
#pragma unroll
      for (int o = 1; o < 64; o <<= 1) v = fmaxf(v, __shfl_xor(v, o, 64));
      mx = fmaxf(mx, v);
    }
    float den = 0.f;
    for (int base = 0; base < deg; base += 64) {
      int j = base + lane;
      float p = (j < deg) ? __expf(lrelu(ss[bucket[start + j]] + sdv) - mx) : 0.f;
#pragma unroll
      for (int o = 1; o < 64; o <<= 1) p += __shfl_xor(p, o, 64);
      den += p;
    }
    const float inv = 1.f / (den + 1e-16f);
    for (int base = 0; base < deg; base += 64) {
      int j = base + lane;
      int s = 0; float par = 0.f;
      if (j < deg) { s = bucket[start + j]; par = __expf(lrelu(ss[s] + sdv) - mx) * inv; }
      int cnt2 = min(64, deg - base);
      int nq = (cnt2 + 3) >> 2;
      for (int q = 0; q < nq; ++q) {
        int slot = q * 4 + eg;
        float al = (slot < cnt2) ? __shfl(par, slot, 64) : 0.f;
        int   sj = __shfl(s, slot < 63 ? slot : 63, 64);
        unsigned sc = min((unsigned)sj, (unsigned)(NN - 1));
        agg_ch4(acA, acB, *(const unsigned*)(h + ((sc << 6) + laneoff)), al);
      }
    }
  }
  // combine the 4 edge subgroups (2 shuffle rounds)
#pragma unroll
  for (int o = 16; o < 64; o <<= 1) {
    f32x2 tv;
    tv[0] = __shfl_xor(acA[0], o, 64); tv[1] = __shfl_xor(acA[1], o, 64); acA += tv;
    tv[0] = __shfl_xor(acB[0], o, 64); tv[1] = __shfl_xor(acB[1], o, 64); acB += tv;
  }
  if (eg == 0) {
    float4 bv = *(const float4*)(bias + cpos * 4);
    float4 r;
    r.x = elu(acA[0] + bv.x);
    r.y = elu(acA[1] + bv.y);
    r.z = elu(acB[0] + bv.z);
    r.w = elu(acB[1] + bv.w);
    *(float4*)(outp + (size_t)d * HID + cpos * 4) = r;
  }
}

// ================= gemm2 (MFMA): full register preload (16 loads in flight) ==========
__global__ __launch_bounds__(256) void gemm2_mfma(
    const __half* __restrict__ o1h, const __half* __restrict__ W2T,
    const float* __restrict__ asrc, const float* __restrict__ adst,
    unsigned char* __restrict__ h2, float* __restrict__ ssrc, float* __restrict__ sdst) {
  __shared__ float hs[16][HID + 1];
  const int m0 = blockIdx.x * 16;
  const int t = threadIdx.x;
  const int wv = t >> 6, lane = t & 63;
  const int lm = lane & 15, quad = lane >> 4;
  const __half* arow = o1h + (size_t)(m0 + lm) * HC1 + quad * 8;
  const __half* brow = W2T + (size_t)(wv * 16 + lm) * HC1 + quad * 8;
  half8 av[8], bv8[8];
#pragma unroll
  for (int i = 0; i < 8; ++i) av[i]  = *(const half8*)(arow + i * 32);
#pragma unroll
  for (int i = 0; i < 8; ++i) bv8[i] = *(const half8*)(brow + i * 32);
  f32x4 acc = {0.f, 0.f, 0.f, 0.f};
#pragma unroll
  for (int i = 0; i < 8; ++i)
    acc = __builtin_amdgcn_mfma_f32_16x16x32_f16(av[i], bv8[i], acc, 0, 0, 0);
#pragma unroll
  for (int r = 0; r < 4; ++r)
    hs[quad * 4 + r][wv * 16 + lm] = acc[r];
  __syncthreads();
  {
    int row = t >> 4, c4 = (t & 15) * 4;
    unsigned pk = pack_fp8x4(hs[row][c4], hs[row][c4 + 1], hs[row][c4 + 2], hs[row][c4 + 3]);
    *(unsigned*)(h2 + (size_t)(m0 + row) * HID + c4) = pk;
  }
  if (t < 64) {
    int task = t >> 1, part = t & 1;
    int r = task >> 1, isdst = task & 1;
    const float* a = isdst ? adst : asrc;
    float s = 0.f;
    int c0 = part * 32;
    for (int c = c0; c < c0 + 32; ++c) s += hs[r][c] * a[c];
    s += __shfl_xor(s, 1, 64);
    if (part == 0) (isdst ? sdst : ssrc)[m0 + r] = s;
  }
}

// ---------------- fused pool + FC + log_softmax (gstart inline): one block/graph -------
__global__ __launch_bounds__(1024) void pool_head_kernel(const float* __restrict__ o2,
                                                         const int* __restrict__ batch,
                                                         const float* __restrict__ fcw,
                                                         const float* __restrict__ fcb,
                                                         float* __restrict__ out) {
  __shared__ float red[16][HID];
  __shared__ int sbound[2];
  int g = blockIdx.x;
  int t = threadIdx.x;
  if (t < 2) {                         // graph boundaries via binary search
    int gg = g + t, lo = 0, hi = NN;
    while (lo < hi) { int mid = (lo + hi) >> 1; if (batch[mid] < gg) lo = mid + 1; else hi = mid; }
    sbound[t] = lo;
  }
  __syncthreads();
  int s0 = sbound[0], s1 = sbound[1];
  int c = t & 63, r = t >> 6;          // 16 node-rows in flight
  float acc = 0.f;
  for (int n = s0 + r; n < s1; n += 16) acc += o2[(size_t)n * HID + c];
  red[r][c] = acc;
  __syncthreads();
  if (r == 0) {                        // threads 0..63 = one wave
    float v = 0.f;
#pragma unroll
    for (int k = 0; k < 16; ++k) v += red[k][c];
    v /= fmaxf((float)(s1 - s0), 1.f);
    float p0 = v * fcw[c * 2 + 0];
    float p1 = v * fcw[c * 2 + 1];
#pragma unroll
    for (int o = 1; o < 64; o <<= 1) {
      p0 += __shfl_xor(p0, o, 64);
      p1 += __shfl_xor(p1, o, 64);
    }
    if (c == 0) {
      float l0 = p0 + fcb[0], l1 = p1 + fcb[1];
      float mx = fmaxf(l0, l1);
      float lse = mx + logf(expf(l0 - mx) + expf(l1 - mx));
      out[g * 2 + 0] = l0 - lse;
      out[g * 2 + 1] = l1 - lse;
    }
  }
}

// ---------------- launch ----------------
extern "C" void kernel_launch(void* const* d_in, const int* in_sizes, int n_in,
                              void* d_out, int out_size, void* d_ws, size_t ws_size,
                              hipStream_t stream) {
  const float* x    = (const float*)d_in[0];
  const int*   ei   = (const int*)d_in[1];
  const int*   batch= (const int*)d_in[2];
  const float* W1   = (const float*)d_in[3];
  const float* as1  = (const float*)d_in[4];
  const float* ad1  = (const float*)d_in[5];
  const float* b1   = (const float*)d_in[6];
  const float* W2   = (const float*)d_in[7];
  const float* as2  = (const float*)d_in[8];
  const float* ad2  = (const float*)d_in[9];
  const float* b2   = (const float*)d_in[10];
  const float* fcw  = (const float*)d_in[11];
  const float* fcb  = (const float*)d_in[12];
  float* out = (float*)d_out;
  float* ws  = (float*)d_ws;

  const int* esrc = ei;
  const int* edst = ei + NE;

  // ---- workspace layout (float units) ----
  size_t off = 0;
  float* hreg  = ws + off; off += (size_t)NN * HC1 / 4;  // h1 fp8 [NN,256] (permuted ch)
  float* o1reg = ws + off; off += (size_t)NN * HC1 / 2;  // o1 fp16 [NN,256] (permuted ch)
  float* l2reg = ws + off; off += (size_t)NN * HC1 / 2;  // h2 fp8 + o2 fp32 (also scmp, earlier)
  float* ss1 = ws + off; off += (size_t)NN * HEADS;
  float* sd1 = ws + off; off += (size_t)NN * HEADS;
  float* ss2 = ws + off; off += NN;
  float* sd2 = ws + off; off += NN;
  __half* W1T = (__half*)(ws + off); off += (size_t)HC1 * F_IN / 2;
  __half* W2T = (__half*)(ws + off); off += (size_t)HID * HC1 / 2;
  float* b1p  = ws + off; off += HC1;                    // permuted bias1
  int* bucket = (int*)(ws + off); off += (size_t)NN * CAP;   // 25.6 MB
  int* cnt    = (int*)(ws + off); off += NN;                 // fully written by phase-2
  unsigned char* h1 = (unsigned char*)hreg;            // [NN, 256] fp8 e4m3 (permuted)
  __half* o1h = (__half*)o1reg;                        // [NN, 256] fp16 (permuted)
  unsigned char* h2 = (unsigned char*)l2reg;           // [NN, 64] fp8 e4m3
  float*  o2  = l2reg + (size_t)NN * HID / 4;          // [NN, 64] fp32
  // scatter staging aliases l2reg (dead until gemm2): 3.4 + 0.33 MB < 25.6 MB
  int* scmp     = (int*)l2reg;                         // [ETOT] packed (src | dlow<<16)
  int* blockcnt = (int*)l2reg + ETOT;                  // [NSB][NCB]
  int* blockoff = blockcnt + (size_t)NSB * NCB;        // [NSB][NCB]

  // ---- prep: transposes + b1 permute (no counter zeroing needed) ----
  prep_kernel<<<(TW_TOT + HC1 + 255) / 256, 256, 0, stream>>>(
      W1, W2, b1, W1T, W2T, b1p);

  // ---- phase-1 atomic-free scatter || layer-1 GEMM (independent; co-scheduled) ----
  gemm1_scatter_kernel<<<NSB + GEMM1_B, 256, 0, stream>>>(
      x, W1T, as1, ad1, h1, ss1, sd1, esrc, edst, blockcnt, blockoff, scmp);

  // ---- phase-2: run-concatenating bucket build (one block per coarse bucket) ----
  bucket_build_kernel<<<NCB, 1024, 0, stream>>>(blockcnt, blockoff, scmp, cnt, bucket);

  // ---- layer 1 gather ----
  gat_gather4_kernel<<<(NN + 3) / 4, 256, 0, stream>>>(cnt, bucket, ss1, sd1, h1, b1p, o1h);

  // ---- layer 2 ----
  gemm2_mfma<<<NN / 16, 256, 0, stream>>>(o1h, W2T, as2, ad2, h2, ss2, sd2);
  gat_gather1_kernel<<<(NN + 3) / 4, 256, 0, stream>>>(cnt, bucket, ss2, sd2, h2, b2, o2);

  // ---- pool + head (fused, gstart inline) ----
  pool_head_kernel<<<NG, 1024, 0, stream>>>(o2, batch, fcw, fcb, out);
}

// Round 14
// 257.053 us; speedup vs baseline: 1.0351x; 1.0351x over previous
//
#include <hip/hip_runtime.h>
#include <hip/hip_fp16.h>
#include <hip/hip_fp8.h>
#include <math.h>

// ---------------- problem constants ----------------
constexpr int NN   = 50000;          // nodes
constexpr int NE   = 800000;         // edges (before self loops)
constexpr int ETOT = NE + NN;        // 850000 with self loops
constexpr int F_IN = 128;
constexpr int HID  = 64;
constexpr int HEADS = 4;
constexpr int HC1  = HEADS * HID;    // 256
constexpr int NG   = 64;             // graphs
constexpr float SLOPE = 0.2f;
constexpr int TW_TOT = F_IN * HC1 + HC1 * HID;   // transpose work items (49152)
constexpr int CAP  = 128;            // bucket capacity per dst (max deg ~45 for this input)
constexpr int GEMM1_B = NN / 16;     // 3125 gemm blocks

// ---- atomic-free two-phase counting scatter ----
constexpr int CB_SHIFT = 7;                      // 128 dsts per coarse bucket
constexpr int NDB  = 1 << CB_SHIFT;              // 128
constexpr int NCB  = (NN + NDB - 1) >> CB_SHIFT; // 391 coarse buckets
constexpr int SEPB = 8192;                       // edges per scatter block
constexpr int SCAT_ITER = SEPB / (256 * 8);      // 4 macro-iterations
constexpr int NSB  = (ETOT + SEPB - 1) / SEPB;   // 104 scatter blocks

// h1/o1 channel permutation: group g = head*16 + lm (4 bytes tn=0..3),
// orig channel = head*64 + tn*16 + lm. Producer packs MFMA regs directly;
// consumers (gather4 groups, b1p, W2T K-axis) all use the same permutation.

typedef _Float16 half8 __attribute__((ext_vector_type(8)));
typedef float f32x4 __attribute__((ext_vector_type(4)));
typedef float f32x2 __attribute__((ext_vector_type(2)));

__device__ __forceinline__ float lrelu(float v) { return v >= 0.f ? v : SLOPE * v; }
// fast elu: exp(v)-1 (abs err ~1e-6 << 4e-3 tolerance; expm1f costs ~25 VALU)
__device__ __forceinline__ float elu(float v) { return v > 0.f ? v : __expf(v) - 1.f; }

// ---- fp8 e4m3 helpers (OCP; gfx950 HW cvt when available) ----
__device__ __forceinline__ unsigned pack_fp8x4(float a, float b, float c, float d) {
#if __has_builtin(__builtin_amdgcn_cvt_pk_fp8_f32)
  int v = 0;
  v = __builtin_amdgcn_cvt_pk_fp8_f32(a, b, v, false);
  v = __builtin_amdgcn_cvt_pk_fp8_f32(c, d, v, true);
  return (unsigned)v;
#else
  __hip_fp8_e4m3 fa(a), fb(b), fc(c), fd(d);
  return (unsigned)fa.__x | ((unsigned)fb.__x << 8) |
         ((unsigned)fc.__x << 16) | ((unsigned)fd.__x << 24);
#endif
}

__device__ __forceinline__ float fp8_1(unsigned byte) {   // manual e4m3fn -> f32
  unsigned s = (byte & 0x80u) << 24;
  unsigned em = (byte & 0x7fu) << 20;
  return __uint_as_float(s | em) * 0x1p+120f;
}

// 4-channel fp8 accumulate: acA gets bytes{0,1}, acB gets bytes{2,3}.
__device__ __forceinline__ void agg_ch4(f32x2& acA, f32x2& acB, unsigned u, float al) {
#if __has_builtin(__builtin_amdgcn_cvt_pk_f32_fp8)
  f32x2 lo = __builtin_amdgcn_cvt_pk_f32_fp8((int)u, false);
  f32x2 hi = __builtin_amdgcn_cvt_pk_f32_fp8((int)u, true);
  f32x2 a2 = {al, al};
  asm("v_pk_fma_f32 %0, %1, %2, %0" : "+v"(acA) : "v"(lo), "v"(a2));
  asm("v_pk_fma_f32 %0, %1, %2, %0" : "+v"(acB) : "v"(hi), "v"(a2));
#else
  acA[0] += al * fp8_1(u & 0xffu);
  acA[1] += al * fp8_1((u >> 8) & 0xffu);
  acB[0] += al * fp8_1((u >> 16) & 0xffu);
  acB[1] += al * fp8_1(u >> 24);
#endif
}

// ---- edge macro-load: 8 edges per thread at e0 (ETOT%8==0, NE%8==0) ----
__device__ __forceinline__ void load_edges8(const int* __restrict__ esrc,
                                            const int* __restrict__ edst,
                                            int e0, int* sarr, int* darr) {
  if (e0 < NE) {
    int4 a = *(const int4*)(esrc + e0);
    int4 b = *(const int4*)(esrc + e0 + 4);
    int4 c = *(const int4*)(edst + e0);
    int4 d4 = *(const int4*)(edst + e0 + 4);
    sarr[0]=a.x; sarr[1]=a.y; sarr[2]=a.z; sarr[3]=a.w;
    sarr[4]=b.x; sarr[5]=b.y; sarr[6]=b.z; sarr[7]=b.w;
    darr[0]=c.x; darr[1]=c.y; darr[2]=c.z; darr[3]=c.w;
    darr[4]=d4.x; darr[5]=d4.y; darr[6]=d4.z; darr[7]=d4.w;
  } else {                                // self-loops
#pragma unroll
    for (int k = 0; k < 8; ++k) { sarr[k] = e0 - NE + k; darr[k] = sarr[k]; }
  }
}

// ================= prep: weight transposes + b1 permute ==============================
__global__ void prep_kernel(const float* __restrict__ W1, const float* __restrict__ W2,
                            const float* __restrict__ b1,
                            __half* __restrict__ W1T, __half* __restrict__ W2T,
                            float* __restrict__ b1p) {
  int i = blockIdx.x * blockDim.x + threadIdx.x;
  if (i < F_IN * HC1) {                       // W1 [128][256] -> W1T [256][128]
    int k = i / HC1, n = i - k * HC1;
    W1T[n * F_IN + k] = __float2half(W1[i]);
  } else if (i < TW_TOT) {                    // W2 [256][64] -> W2T [64][256], K permuted
    int j = i - F_IN * HC1;
    int k = j / HID, n = j - k * HID;
    // kp(k): head=k>>6, tn=(k>>4)&3, lm=k&15 -> g=head*16+lm, k' = g*4+tn
    int kp = (((k >> 6) * 16 + (k & 15)) << 2) | ((k >> 4) & 3);
    W2T[n * HC1 + kp] = __float2half(W2[j]);
  } else if (i < TW_TOT + HC1) {
    int g4 = i - TW_TOT;
    int g = g4 >> 2, tn = g4 & 3;
    b1p[g4] = b1[(g >> 4) * 64 + tn * 16 + (g & 15)];
  }
}

// ================= mega kernel: atomic-free scatter blocks || gemm1 blocks ===========
__global__ __launch_bounds__(256) void gemm1_scatter_kernel(
    const float* __restrict__ x, const __half* __restrict__ W1T,
    const float* __restrict__ asrc, const float* __restrict__ adst,
    unsigned char* __restrict__ h1, float* __restrict__ ssrc, float* __restrict__ sdst,
    const int* __restrict__ esrc, const int* __restrict__ edst,
    int* __restrict__ blockcnt, int* __restrict__ blockoff, int* __restrict__ scmp) {
  const int t = threadIdx.x;
  if (blockIdx.x < NSB) {
    // ---- phase-1: block-local segmented scatter, ZERO global atomics ----
    __shared__ int hist[512];     // coarse histogram (padded to 512 for scan)
    __shared__ int buf2[512];     // scan double-buffer / base
    __shared__ int cursor[512];   // per-cb write cursor
    for (int i = t; i < 512; i += 256) { hist[i] = 0; cursor[i] = 0; }
    __syncthreads();
    const int ebase = blockIdx.x * SEPB;
    // pass A: histogram
    for (int it = 0; it < SCAT_ITER; ++it) {
      int e0 = ebase + it * 2048 + t * 8;
      if (e0 < ETOT) {
        int sarr[8], darr[8];
        load_edges8(esrc, edst, e0, sarr, darr);
#pragma unroll
        for (int k = 0; k < 8; ++k) atomicAdd(&hist[darr[k] >> CB_SHIFT], 1);
      }
    }
    __syncthreads();
    // per-block counts out (coalesced)
    for (int i = t; i < NCB; i += 256) blockcnt[blockIdx.x * NCB + i] = hist[i];
    // Hillis-Steele inclusive scan over 512 entries
    int* src = hist; int* dst = buf2;
    for (int off = 1; off < 512; off <<= 1) {
      for (int i = t; i < 512; i += 256) {
        int v = src[i];
        if (i >= off) v += src[i - off];
        dst[i] = v;
      }
      __syncthreads();
      int* tmp = src; src = dst; dst = tmp;
    }
    // exclusive base into dst; offsets out
    for (int i = t; i < NCB; i += 256) {
      int b = (i == 0) ? 0 : src[i - 1];
      dst[i] = b;
      blockoff[blockIdx.x * NCB + i] = ebase + b;
    }
    __syncthreads();
    // pass B: reload edges (L2-hot) and pack grouped-by-cb into own segment
    for (int it = 0; it < SCAT_ITER; ++it) {
      int e0 = ebase + it * 2048 + t * 8;
      if (e0 < ETOT) {
        int sarr[8], darr[8];
        load_edges8(esrc, edst, e0, sarr, darr);
#pragma unroll
        for (int k = 0; k < 8; ++k) {
          int d = darr[k];
          int cb = d >> CB_SHIFT;
          int pkv = sarr[k] | ((d & (NDB - 1)) << 16);   // src < 65536 fits 16 bits
          int slot = dst[cb] + atomicAdd(&cursor[cb], 1);  // LDS only
          scmp[ebase + slot] = pkv;                        // dense, own segment
        }
      }
    }
    return;
  }
  // ---- gemm1 part: NO LDS. Full register preload before MFMA. ----
  const int m0 = (blockIdx.x - NSB) * 16;
  const int wv = t >> 6, lane = t & 63;
  const int lm = lane & 15, quad = lane >> 4;
  const int n0 = wv * 64;       // wave wv owns head wv's 64 channels
  const float*  arow  = x   + (size_t)(m0 + lm) * F_IN + quad * 8;
  const __half* wbase = W1T + (size_t)(n0 + lm) * F_IN + quad * 8;
  // issue ALL loads first: 8x float4 (x) + 16x half8 (W1T)
  float4 xf[8];
#pragma unroll
  for (int it = 0; it < 4; ++it) {
    xf[it * 2 + 0] = *(const float4*)(arow + it * 32);
    xf[it * 2 + 1] = *(const float4*)(arow + it * 32 + 4);
  }
  half8 bh[4][4];   // [tn][it]
#pragma unroll
  for (int tn = 0; tn < 4; ++tn)
#pragma unroll
    for (int it = 0; it < 4; ++it)
      bh[tn][it] = *(const half8*)(wbase + tn * 16 * F_IN + it * 32);
  // convert + MFMA (all operands live in registers)
  f32x4 acc[4] = {{0.f,0.f,0.f,0.f},{0.f,0.f,0.f,0.f},{0.f,0.f,0.f,0.f},{0.f,0.f,0.f,0.f}};
#pragma unroll
  for (int it = 0; it < 4; ++it) {
    float4 u = xf[it * 2 + 0], v = xf[it * 2 + 1];
    half8 a;
    a[0]=(_Float16)u.x; a[1]=(_Float16)u.y; a[2]=(_Float16)u.z; a[3]=(_Float16)u.w;
    a[4]=(_Float16)v.x; a[5]=(_Float16)v.y; a[6]=(_Float16)v.z; a[7]=(_Float16)v.w;
#pragma unroll
    for (int tn = 0; tn < 4; ++tn)
      acc[tn] = __builtin_amdgcn_mfma_f32_16x16x32_f16(a, bh[tn][it], acc[tn], 0, 0, 0);
  }
  // acc[tn][r] = h[m0 + quad*4 + r][n0 + tn*16 + lm]
  // scores from registers: s[row][wv] = sum acc[tn][r] * a[n0+tn*16+lm], reduce over lm
  {
    float asv[4], adv[4];
#pragma unroll
    for (int tn = 0; tn < 4; ++tn) {
      asv[tn] = asrc[n0 + tn * 16 + lm];
      adv[tn] = adst[n0 + tn * 16 + lm];
    }
#pragma unroll
    for (int r = 0; r < 4; ++r) {
      float ps = acc[0][r] * asv[0] + acc[1][r] * asv[1]
               + acc[2][r] * asv[2] + acc[3][r] * asv[3];
      float pd = acc[0][r] * adv[0] + acc[1][r] * adv[1]
               + acc[2][r] * adv[2] + acc[3][r] * adv[3];
#pragma unroll
      for (int o = 1; o < 16; o <<= 1) {
        ps += __shfl_xor(ps, o, 64);
        pd += __shfl_xor(pd, o, 64);
      }
      if (lm == 0) {
        int row = m0 + quad * 4 + r;
        ssrc[row * HEADS + wv] = ps;
        sdst[row * HEADS + wv] = pd;
      }
    }
  }
  // h1 fp8 pack directly from registers into permuted layout:
  // group g = wv*16+lm, byte tn; addr = node*256 + g*4
  {
    const unsigned goff = (unsigned)((wv * 16 + lm) * 4);
#pragma unroll
    for (int r = 0; r < 4; ++r) {
      unsigned pk = pack_fp8x4(acc[0][r], acc[1][r], acc[2][r], acc[3][r]);
      *(unsigned*)(h1 + (size_t)(m0 + quad * 4 + r) * HC1 + goff) = pk;
    }
  }
}

// ================= phase-2: concatenate per-block runs into per-dst buckets =========
// One block per coarse bucket; wave w walks runs b = w, w+16, ...; LDS-only atomics.
__global__ __launch_bounds__(1024) void bucket_build_kernel(
    const int* __restrict__ blockcnt, const int* __restrict__ blockoff,
    const int* __restrict__ scmp, int* __restrict__ cnt, int* __restrict__ bucket) {
  __shared__ int hist2[NDB];
  const int cb = blockIdx.x, t = threadIdx.x;
  const int wv = t >> 6, lane = t & 63;
  if (t < NDB) hist2[t] = 0;
  __syncthreads();
  for (int b = wv; b < NSB; b += 16) {
    int n   = blockcnt[b * NCB + cb];
    int off = blockoff[b * NCB + cb];
    for (int j = lane; j < n; j += 64) {
      int v = scmp[off + j];
      int s = v & 0xFFFF, dlow = (v >> 16) & (NDB - 1);
      int l = atomicAdd(&hist2[dlow], 1);
      if (l < CAP) bucket[(size_t)((cb << CB_SHIFT) | dlow) * CAP + l] = s;
    }
  }
  __syncthreads();
  int d = (cb << CB_SHIFT) | t;
  if (t < NDB && d < NN) cnt[d] = hist2[t];
}

// ================= fused GAT gather, layer 1 (H=4, fp8 h, permuted channels) =========
// One wave per dst; lane owns group lane (4 channels) -> ONE coalesced dword per edge.
// Bucket quads prefetched; saddr-form h loads; fast elu. (Best-measured structure, R9.)
__global__ __launch_bounds__(256) void gat_gather4_kernel(
    const int* __restrict__ cnt, const int* __restrict__ bucket,
    const float* __restrict__ ss, const float* __restrict__ sd,
    const unsigned char* __restrict__ h, const float* __restrict__ biasp,
    __half* __restrict__ outp) {
  __shared__ float paS[4][HEADS][40];    // [wave][head][slot], pitch 40 for bank spread
  const int wv   = threadIdx.x >> 6;
  const int lane = threadIdx.x & 63;
  const int d    = (blockIdx.x * 256 + threadIdx.x) >> 6;
  if (d >= NN) return;
  const int start = d * CAP;
  const int deg   = min(cnt[d], CAP);
  const int hsel  = lane & 3;            // score-phase head
  const int j0    = lane >> 2;           // score-phase edge
  const int head  = lane >> 4;           // agg-phase head of this lane's group
  const float sdv = sd[d * 4 + hsel];
  float (*pa)[40] = paS[wv];

  f32x2 acA = {0.f, 0.f}, acB = {0.f, 0.f};
  const unsigned laneoff = (unsigned)(lane * 4);   // 32-bit lane offset; base h stays SGPR

  if (deg <= 32) {
    // prefetch all 8 bucket quads up-front (in-bounds: CAP=128; pad slots get alpha 0)
    int4 svq[8];
#pragma unroll
    for (int q = 0; q < 8; ++q) svq[q] = *(const int4*)(bucket + start + q * 4);
    int s0 = 0, s1 = 0;
    float v0 = -INFINITY, v1 = -INFINITY;
    if (j0 < deg)      { s0 = bucket[start + j0];      v0 = lrelu(ss[s0 * 4 + hsel] + sdv); }
    if (j0 + 16 < deg) { s1 = bucket[start + j0 + 16]; v1 = lrelu(ss[s1 * 4 + hsel] + sdv); }
    float mx = fmaxf(v0, v1);
#pragma unroll
    for (int o = 4; o < 64; o <<= 1) mx = fmaxf(mx, __shfl_xor(mx, o, 64));
    float p0 = (j0 < deg)      ? __expf(v0 - mx) : 0.f;
    float p1 = (j0 + 16 < deg) ? __expf(v1 - mx) : 0.f;
    float den = p0 + p1;
#pragma unroll
    for (int o = 4; o < 64; o <<= 1) den += __shfl_xor(den, o, 64);
    const float inv = 1.f / (den + 1e-16f);
    pa[hsel][j0]      = p0 * inv;        // zeros where invalid -> pad slots are 0
    pa[hsel][j0 + 16] = p1 * inv;
    const int nq = (deg + 3) >> 2;
#pragma unroll
    for (int q = 0; q < 8; ++q) {
      if (q >= nq) break;                // wave-uniform exit; q compile-time per block
      float4 av = *(const float4*)&pa[head][q * 4];
      {
        unsigned sj = min((unsigned)svq[q].x, (unsigned)(NN - 1));
        agg_ch4(acA, acB, *(const unsigned*)(h + ((sj << 8) + laneoff)), av.x);
      }
      {
        unsigned sj = min((unsigned)svq[q].y, (unsigned)(NN - 1));
        agg_ch4(acA, acB, *(const unsigned*)(h + ((sj << 8) + laneoff)), av.y);
      }
      {
        unsigned sj = min((unsigned)svq[q].z, (unsigned)(NN - 1));
        agg_ch4(acA, acB, *(const unsigned*)(h + ((sj << 8) + laneoff)), av.z);
      }
      {
        unsigned sj = min((unsigned)svq[q].w, (unsigned)(NN - 1));
        agg_ch4(acA, acB, *(const unsigned*)(h + ((sj << 8) + laneoff)), av.w);
      }
    }
  } else {
    // chunked (rare): 16 edges per chunk, alphas staged per chunk
    float mx = -INFINITY;
    for (int base = 0; base < deg; base += 16) {
      int j = base + j0;
      float v = (j < deg) ? lrelu(ss[bucket[start + j] * 4 + hsel] + sdv) : -INFINITY;
#pragma unroll
      for (int o = 4; o < 64; o <<= 1) v = fmaxf(v, __shfl_xor(v, o, 64));
      mx = fmaxf(mx, v);
    }
    float den = 0.f;
    for (int base = 0; base < deg; base += 16) {
      int j = base + j0;
      float p = (j < deg) ? __expf(lrelu(ss[bucket[start + j] * 4 + hsel] + sdv) - mx) : 0.f;
#pragma unroll
      for (int o = 4; o < 64; o <<= 1) p += __shfl_xor(p, o, 64);
      den += p;
    }
    const float inv = 1.f / (den + 1e-16f);
    for (int base = 0; base < deg; base += 16) {
      int j = base + j0;
      float pav = 0.f;
      if (j < deg) pav = __expf(lrelu(ss[bucket[start + j] * 4 + hsel] + sdv) - mx) * inv;
      pa[hsel][j0] = pav;
      const int m  = min(16, deg - base);
      const int nq = (m + 3) >> 2;
      for (int q = 0; q < nq; ++q) {
        int4   sv = *(const int4*)(bucket + start + base + q * 4);
        float4 av = *(const float4*)&pa[head][q * 4];
        {
          unsigned sj = min((unsigned)sv.x, (unsigned)(NN - 1));
          agg_ch4(acA, acB, *(const unsigned*)(h + ((sj << 8) + laneoff)), av.x);
        }
        {
          unsigned sj = min((unsigned)sv.y, (unsigned)(NN - 1));
          agg_ch4(acA, acB, *(const unsigned*)(h + ((sj << 8) + laneoff)), av.y);
        }
        {
          unsigned sj = min((unsigned)sv.z, (unsigned)(NN - 1));
          agg_ch4(acA, acB, *(const unsigned*)(h + ((sj << 8) + laneoff)), av.z);
        }
        {
          unsigned sj = min((unsigned)sv.w, (unsigned)(NN - 1));
          agg_ch4(acA, acB, *(const unsigned*)(h + ((sj << 8) + laneoff)), av.w);
        }
      }
    }
  }
  // epilogue: permuted bias + fast elu + fp16 store (permuted o1), 8B/lane contiguous
  float4 bv = *(const float4*)(biasp + lane * 4);
  float e0 = elu(acA[0] + bv.x), e1 = elu(acA[1] + bv.y);
  float e2 = elu(acB[0] + bv.z), e3 = elu(acB[1] + bv.w);
  union { __half2 h2[2]; uint2 u; } pk;
  pk.h2[0] = __floats2half2_rn(e0, e1);
  pk.h2[1] = __floats2half2_rn(e2, e3);
  *(uint2*)(outp + (size_t)d * HC1 + lane * 4) = pk.u;
}

// ================= fused GAT gather, layer 2 (H=1, fp8 h): NO LDS ====================
// One wave per dst; srcs+alphas live in registers, broadcast via __shfl from lane=slot.
// saddr-form h loads (uniform base + 32-bit offset); fast elu.
__global__ __launch_bounds__(256) void gat_gather1_kernel(
    const int* __restrict__ cnt, const int* __restrict__ bucket,
    const float* __restrict__ ss, const float* __restrict__ sd,
    const unsigned char* __restrict__ h, const float* __restrict__ bias,
    float* __restrict__ outp) {
  const int lane = threadIdx.x & 63;
  const int d    = (blockIdx.x * 256 + threadIdx.x) >> 6;
  if (d >= NN) return;
  const int start = d * CAP;
  const int deg   = min(cnt[d], CAP);
  const int eg    = lane >> 4;    // edge subgroup (0..3)
  const int cpos  = lane & 15;    // 4B chunk within 64B fp8 row
  const float sdv = sd[d];
  f32x2 acA = {0.f, 0.f}, acB = {0.f, 0.f};
  const unsigned laneoff = (unsigned)(cpos * 4);

  if (deg <= 64) {
    int s = 0; float v = -INFINITY;
    if (lane < deg) { s = bucket[start + lane]; v = lrelu(ss[s] + sdv); }
    float mx = v;
#pragma unroll
    for (int o = 1; o < 64; o <<= 1) mx = fmaxf(mx, __shfl_xor(mx, o, 64));
    float p = (lane < deg) ? __expf(v - mx) : 0.f;
    float den = p;
#pragma unroll
    for (int o = 1; o < 64; o <<= 1) den += __shfl_xor(den, o, 64);
    const float par = p / (den + 1e-16f);   // 0 for lanes >= deg -> pad alpha 0
    const int nq = (deg + 3) >> 2;
#pragma unroll
    for (int q = 0; q < 16; ++q) {
      if (q >= nq) break;                   // wave-uniform exit
      int slot = q * 4 + eg;
      float al = __shfl(par, slot, 64);     // 0 automatically when slot >= deg
      int   sj = __shfl(s, slot, 64);       // 0 (valid row) when slot >= deg
      unsigned sc = min((unsigned)sj, (unsigned)(NN - 1));
      agg_ch4(acA, acB, *(const unsigned*)(h + ((sc << 6) + laneoff)), al);
    }
  } else {
    float mx = -INFINITY;
    for (int base = 0; base < deg; base += 64) {
      int j = base + lane;
      float v = (j < deg) ? lrelu(ss[bucket[start + j]] + sdv) : -INFINITY;
#pragma unroll
      for (int o = 1; o < 64; o <<= 1) v = fmaxf(v, __shfl_xor(v, o, 64));
      mx = fmaxf(mx, v);
    }
    float den = 0.f;
    for (int base = 0; base < deg; base += 64) {
      int j = base + lane;
      float p = (j < deg) ? __expf(lrelu(ss[bucket[start + j]] + sdv) - mx) : 0.f;
#pragma unroll
      for (int o = 1; o < 64; o <<= 1) p += __shfl_xor(p, o, 64);
      den += p;
    }
    const float inv = 1.f / (den + 1e-16f);
    for (int base = 0; base < deg; base += 64) {
      int j = base + lane;
      int s = 0; float par = 0.f;
      if (j < deg) { s = bucket[start + j]; par = __expf(lrelu(ss[s] + sdv) - mx) * inv; }
      int cnt2 = min(64, deg - base);
      int nq = (cnt2 + 3) >> 2;
      for (int q = 0; q < nq; ++q) {
        int slot = q * 4 + eg;
        float al = (slot < cnt2) ? __shfl(par, slot, 64) : 0.f;
        int   sj = __shfl(s, slot < 63 ? slot : 63, 64);
        unsigned sc = min((unsigned)sj, (unsigned)(NN - 1));
        agg_ch4(acA, acB, *(const unsigned*)(h + ((sc << 6) + laneoff)), al);
      }
    }
  }
  // combine the 4 edge subgroups (2 shuffle rounds)
#pragma unroll
  for (int o = 16; o < 64; o <<= 1) {
    f32x2 tv;
    tv[0] = __shfl_xor(acA[0], o, 64); tv[1] = __shfl_xor(acA[1], o, 64); acA += tv;
    tv[0] = __shfl_xor(acB[0], o, 64); tv[1] = __shfl_xor(acB[1], o, 64); acB += tv;
  }
  if (eg == 0) {
    float4 bv = *(const float4*)(bias + cpos * 4);
    float4 r;
    r.x = elu(acA[0] + bv.x);
    r.y = elu(acA[1] + bv.y);
    r.z = elu(acB[0] + bv.z);
    r.w = elu(acB[1] + bv.w);
    *(float4*)(outp + (size_t)d * HID + cpos * 4) = r;
  }
}

// ================= gemm2 (MFMA): full register preload (16 loads in flight) ==========
__global__ __launch_bounds__(256) void gemm2_mfma(
    const __half* __restrict__ o1h, const __half* __restrict__ W2T,
    const float* __restrict__ asrc, const float* __restrict__ adst,
    unsigned char* __restrict__ h2, float* __restrict__ ssrc, float* __restrict__ sdst) {
  __shared__ float hs[16][HID + 1];
  const int m0 = blockIdx.x * 16;
  const int t = threadIdx.x;
  const int wv = t >> 6, lane = t & 63;
  const int lm = lane & 15, quad = lane >> 4;
  const __half* arow = o1h + (size_t)(m0 + lm) * HC1 + quad * 8;
  const __half* brow = W2T + (size_t)(wv * 16 + lm) * HC1 + quad * 8;
  // issue all 16 loads before any MFMA
  half8 av[8], bv8[8];
#pragma unroll
  for (int i = 0; i < 8; ++i) av[i]  = *(const half8*)(arow + i * 32);
#pragma unroll
  for (int i = 0; i < 8; ++i) bv8[i] = *(const half8*)(brow + i * 32);
  f32x4 acc = {0.f, 0.f, 0.f, 0.f};
#pragma unroll
  for (int i = 0; i < 8; ++i)
    acc = __builtin_amdgcn_mfma_f32_16x16x32_f16(av[i], bv8[i], acc, 0, 0, 0);
#pragma unroll
  for (int r = 0; r < 4; ++r)
    hs[quad * 4 + r][wv * 16 + lm] = acc[r];
  __syncthreads();
  {
    int row = t >> 4, c4 = (t & 15) * 4;
    unsigned pk = pack_fp8x4(hs[row][c4], hs[row][c4 + 1], hs[row][c4 + 2], hs[row][c4 + 3]);
    *(unsigned*)(h2 + (size_t)(m0 + row) * HID + c4) = pk;
  }
  if (t < 64) {
    int task = t >> 1, part = t & 1;
    int r = task >> 1, isdst = task & 1;
    const float* a = isdst ? adst : asrc;
    float s = 0.f;
    int c0 = part * 32;
    for (int c = c0; c < c0 + 32; ++c) s += hs[r][c] * a[c];
    s += __shfl_xor(s, 1, 64);
    if (part == 0) (isdst ? sdst : ssrc)[m0 + r] = s;
  }
}

// ---------------- fused pool + FC + log_softmax (gstart inline): one block/graph -------
__global__ __launch_bounds__(1024) void pool_head_kernel(const float* __restrict__ o2,
                                                         const int* __restrict__ batch,
                                                         const float* __restrict__ fcw,
                                                         const float* __restrict__ fcb,
                                                         float* __restrict__ out) {
  __shared__ float red[16][HID];
  __shared__ int sbound[2];
  int g = blockIdx.x;
  int t = threadIdx.x;
  if (t < 2) {                         // graph boundaries via binary search
    int gg = g + t, lo = 0, hi = NN;
    while (lo < hi) { int mid = (lo + hi) >> 1; if (batch[mid] < gg) lo = mid + 1; else hi = mid; }
    sbound[t] = lo;
  }
  __syncthreads();
  int s0 = sbound[0], s1 = sbound[1];
  int c = t & 63, r = t >> 6;          // 16 node-rows in flight
  float acc = 0.f;
  for (int n = s0 + r; n < s1; n += 16) acc += o2[(size_t)n * HID + c];
  red[r][c] = acc;
  __syncthreads();
  if (r == 0) {                        // threads 0..63 = one wave
    float v = 0.f;
#pragma unroll
    for (int k = 0; k < 16; ++k) v += red[k][c];
    v /= fmaxf((float)(s1 - s0), 1.f);
    float p0 = v * fcw[c * 2 + 0];
    float p1 = v * fcw[c * 2 + 1];
#pragma unroll
    for (int o = 1; o < 64; o <<= 1) {
      p0 += __shfl_xor(p0, o, 64);
      p1 += __shfl_xor(p1, o, 64);
    }
    if (c == 0) {
      float l0 = p0 + fcb[0], l1 = p1 + fcb[1];
      float mx = fmaxf(l0, l1);
      float lse = mx + logf(expf(l0 - mx) + expf(l1 - mx));
      out[g * 2 + 0] = l0 - lse;
      out[g * 2 + 1] = l1 - lse;
    }
  }
}

// ---------------- launch ----------------
extern "C" void kernel_launch(void* const* d_in, const int* in_sizes, int n_in,
                              void* d_out, int out_size, void* d_ws, size_t ws_size,
                              hipStream_t stream) {
  const float* x    = (const float*)d_in[0];
  const int*   ei   = (const int*)d_in[1];
  const int*   batch= (const int*)d_in[2];
  const float* W1   = (const float*)d_in[3];
  const float* as1  = (const float*)d_in[4];
  const float* ad1  = (const float*)d_in[5];
  const float* b1   = (const float*)d_in[6];
  const float* W2   = (const float*)d_in[7];
  const float* as2  = (const float*)d_in[8];
  const float* ad2  = (const float*)d_in[9];
  const float* b2   = (const float*)d_in[10];
  const float* fcw  = (const float*)d_in[11];
  const float* fcb  = (const float*)d_in[12];
  float* out = (float*)d_out;
  float* ws  = (float*)d_ws;

  const int* esrc = ei;
  const int* edst = ei + NE;

  // ---- workspace layout (float units) ----
  size_t off = 0;
  float* hreg  = ws + off; off += (size_t)NN * HC1 / 4;  // h1 fp8 [NN,256] (permuted ch)
  float* o1reg = ws + off; off += (size_t)NN * HC1 / 2;  // o1 fp16 [NN,256] (permuted ch)
  float* l2reg = ws + off; off += (size_t)NN * HC1 / 2;  // h2 fp8 + o2 fp32 (also scmp, earlier)
  float* ss1 = ws + off; off += (size_t)NN * HEADS;
  float* sd1 = ws + off; off += (size_t)NN * HEADS;
  float* ss2 = ws + off; off += NN;
  float* sd2 = ws + off; off += NN;
  __half* W1T = (__half*)(ws + off); off += (size_t)HC1 * F_IN / 2;
  __half* W2T = (__half*)(ws + off); off += (size_t)HID * HC1 / 2;
  float* b1p  = ws + off; off += HC1;                    // permuted bias1
  int* bucket = (int*)(ws + off); off += (size_t)NN * CAP;   // 25.6 MB
  int* cnt    = (int*)(ws + off); off += NN;                 // fully written by phase-2
  unsigned char* h1 = (unsigned char*)hreg;            // [NN, 256] fp8 e4m3 (permuted)
  __half* o1h = (__half*)o1reg;                        // [NN, 256] fp16 (permuted)
  unsigned char* h2 = (unsigned char*)l2reg;           // [NN, 64] fp8 e4m3
  float*  o2  = l2reg + (size_t)NN * HID / 4;          // [NN, 64] fp32
  // scatter staging aliases l2reg (dead until gemm2): 3.4 + 0.33 MB < 25.6 MB
  int* scmp     = (int*)l2reg;                         // [ETOT] packed (src | dlow<<16)
  int* blockcnt = (int*)l2reg + ETOT;                  // [NSB][NCB]
  int* blockoff = blockcnt + (size_t)NSB * NCB;        // [NSB][NCB]

  // ---- prep: transposes + b1 permute (no counter zeroing needed) ----
  prep_kernel<<<(TW_TOT + HC1 + 255) / 256, 256, 0, stream>>>(
      W1, W2, b1, W1T, W2T, b1p);

  // ---- phase-1 atomic-free scatter || layer-1 GEMM (independent; co-scheduled) ----
  gemm1_scatter_kernel<<<NSB + GEMM1_B, 256, 0, stream>>>(
      x, W1T, as1, ad1, h1, ss1, sd1, esrc, edst, blockcnt, blockoff, scmp);

  // ---- phase-2: run-concatenating bucket build (one block per coarse bucket) ----
  bucket_build_kernel<<<NCB, 1024, 0, stream>>>(blockcnt, blockoff, scmp, cnt, bucket);

  // ---- layer 1 gather ----
  gat_gather4_kernel<<<(NN + 3) / 4, 256, 0, stream>>>(cnt, bucket, ss1, sd1, h1, b1p, o1h);

  // ---- layer 2 ----
  gemm2_mfma<<<NN / 16, 256, 0, stream>>>(o1h, W2T, as2, ad2, h2, ss2, sd2);
  gat_gather1_kernel<<<(NN + 3) / 4, 256, 0, stream>>>(cnt, bucket, ss2, sd2, h2, b2, o2);

  // ---- pool + head (fused, gstart inline) ----
  pool_head_kernel<<<NG, 1024, 0, stream>>>(o2, batch, fcw, fcb, out);
}